// Round 14
// baseline (106.452 us; speedup 1.0000x reference)
//
#include <hip/hip_runtime.h>
#include <cstdint>

#define Bsz 2
#define Lsz 2048
#define Dm  512
#define Nst 64
#define Rr  32
#define Ee  160   // r + 2n
#define NCHUNK 64
#define CLEN   32
#define L2E 1.44269504f
#define LN2 0.69314718f

typedef __bf16  bf16x8 __attribute__((ext_vector_type(8)));
typedef float   f32x4  __attribute__((ext_vector_type(4)));
typedef unsigned short u16x8 __attribute__((ext_vector_type(8)));

__device__ __forceinline__ float rdlane(float v, int l) {
    return __int_as_float(__builtin_amdgcn_readlane(__float_as_int(v), l));
}
// raw v_exp_f32 / v_log_f32 (log2). All hot exp args are <= 0.
__device__ __forceinline__ float fexp2(float x) { return __builtin_amdgcn_exp2f(x); }
__device__ __forceinline__ float flog2(float x) { return __builtin_amdgcn_logf(x); }
__device__ __forceinline__ uint32_t bf16r(float f) {   // RNE to bf16 bits
    uint32_t u = __float_as_uint(f);
    u += 0x7FFFu + ((u >> 16) & 1u);
    return u >> 16;
}
__device__ __forceinline__ float bf2f(unsigned short v) {
    return __uint_as_float((uint32_t)v << 16);
}

// ---------------- Kcast: fp32 -> bf16 (RNE) for x and W in one launch ----------------
__global__ __launch_bounds__(256) void kcast2(const float* __restrict__ a,
                                              unsigned short* __restrict__ oa, int na8,
                                              const float* __restrict__ b,
                                              unsigned short* __restrict__ ob, int nb8) {
    int gid = blockIdx.x * 256 + threadIdx.x;
    const float* in; unsigned short* op; int idx;
    if (gid < na8) { in = a; op = oa; idx = gid; }
    else { idx = gid - na8; if (idx >= nb8) return; in = b; op = ob; }
    const float4* ip = reinterpret_cast<const float4*>(in) + (size_t)idx * 2;
    float4 v0 = ip[0], v1 = ip[1];
    float vv[8] = {v0.x, v0.y, v0.z, v0.w, v1.x, v1.y, v1.z, v1.w};
    u16x8 r;
    #pragma unroll
    for (int j = 0; j < 8; ++j) r[j] = (unsigned short)bf16r(vv[j]);
    *reinterpret_cast<u16x8*>(op + (size_t)idx * 8) = r;
}

// ---------------- K1: xdbl = x @ W^T via MFMA bf16 ----------------
__global__ __launch_bounds__(256) void k1_mfma(const unsigned short* __restrict__ xbf,
                                               const unsigned short* __restrict__ wbf,
                                               float* __restrict__ xdbl) {
    const int tid = threadIdx.x;
    const int wv = tid >> 6, lane = tid & 63;
    const int ng = blockIdx.x % 10, mg = blockIdx.x / 10;
    const int m0 = mg * 64 + wv * 16;
    const int n0 = ng * 16;
    const int ra = lane & 15, kg = lane >> 4;
    const unsigned short* ap = xbf + (size_t)(m0 + ra) * Dm + kg * 8;
    const unsigned short* bp = wbf + (size_t)(n0 + ra) * Dm + kg * 8;
    f32x4 acc = {0.f, 0.f, 0.f, 0.f};
    #pragma unroll
    for (int ks = 0; ks < 16; ++ks) {
        bf16x8 a = *reinterpret_cast<const bf16x8*>(ap + ks * 32);
        bf16x8 b = *reinterpret_cast<const bf16x8*>(bp + ks * 32);
        acc = __builtin_amdgcn_mfma_f32_16x16x32_bf16(a, b, acc, 0, 0, 0);
    }
    // C/D: col = lane&15, row = (lane>>4)*4 + reg   [m89/m91-verified]
    float* dp = xdbl + (size_t)(m0 + kg * 4) * Ee + n0 + ra;
    dp[0]      = acc[0];
    dp[Ee]     = acc[1];
    dp[2 * Ee] = acc[2];
    dp[3 * Ee] = acc[3];
}

// ------- K2: delta = softplus(delta_r @ W_dt^T + b_dt);
//   stores: PACKED ddt (lo16 = delta bf16, hi16 = du bf16) in (b,d,l);
//           sumdl = per-32-step sums of ROUNDED delta;
//           Bt/Ct: chunk-tiled (b, c, n, t) bf16 transposes of B/C (dt==0 blocks) -------
__global__ __launch_bounds__(256) void k2_delta(const float* __restrict__ xdbl,
                                                const float* __restrict__ x,
                                                const float* __restrict__ Wdt,
                                                const float* __restrict__ bdt,
                                                float* __restrict__ ddt,
                                                float* __restrict__ sumdl,
                                                unsigned short* __restrict__ Bt,
                                                unsigned short* __restrict__ Ct) {
    __shared__ float dr[64][33];
    __shared__ float wd[64][32];
    __shared__ float pt[64][65];
    const int tid = threadIdx.x;
    const int lt = blockIdx.x & 31;
    const int dt = (blockIdx.x >> 5) & 7;
    const int b  = blockIdx.x >> 8;
    const int l0 = lt * 64, d0 = dt * 64;

    for (int i = tid; i < 512; i += 256) {
        int l = i >> 3, j4 = i & 7;
        const float4 v = *reinterpret_cast<const float4*>(
            xdbl + (size_t)(b * Lsz + l0 + l) * Ee + j4 * 4);
        dr[l][j4 * 4 + 0] = v.x; dr[l][j4 * 4 + 1] = v.y;
        dr[l][j4 * 4 + 2] = v.z; dr[l][j4 * 4 + 3] = v.w;
    }
    for (int i = tid; i < 512; i += 256) {
        int dd = i >> 3, j4 = i & 7;
        *reinterpret_cast<float4*>(&wd[dd][j4 * 4]) =
            *reinterpret_cast<const float4*>(Wdt + (size_t)(d0 + dd) * Rr + j4 * 4);
    }
    __syncthreads();

    const int w = tid >> 6, lane = tid & 63;
    float drr[32];
    #pragma unroll
    for (int j = 0; j < 32; ++j) drr[j] = dr[lane][j];

    float xv[16];
    {
        const float* xp = x + (size_t)(b * Lsz + l0 + lane) * Dm + d0 + w * 16;
        #pragma unroll
        for (int q = 0; q < 4; ++q) {
            float4 v = reinterpret_cast<const float4*>(xp)[q];
            xv[q*4] = v.x; xv[q*4+1] = v.y; xv[q*4+2] = v.z; xv[q*4+3] = v.w;
        }
    }

    float dl[16];
    #pragma unroll
    for (int i = 0; i < 16; ++i) {
        int dd = w * 16 + i;
        float z = bdt[d0 + dd];
        const float4* wr = reinterpret_cast<const float4*>(&wd[dd][0]);
        #pragma unroll
        for (int j4 = 0; j4 < 8; ++j4) {
            float4 wv = wr[j4];
            z = fmaf(drr[j4*4+0], wv.x, z);
            z = fmaf(drr[j4*4+1], wv.y, z);
            z = fmaf(drr[j4*4+2], wv.z, z);
            z = fmaf(drr[j4*4+3], wv.w, z);
        }
        // softplus(z) = max(z,0) + ln(1 + exp(-|z|)), raw exp2/log2 path
        float t = fexp2(-fabsf(z) * L2E);
        dl[i] = fmaxf(z, 0.f) + flog2(1.f + t) * LN2;
    }

    #pragma unroll
    for (int i = 0; i < 16; ++i) {
        uint32_t db = bf16r(dl[i]);
        uint32_t ub = bf16r(dl[i] * xv[i]);
        pt[w * 16 + i][lane] = __uint_as_float(db | (ub << 16));
    }
    __syncthreads();
    for (int i = tid; i < 4096; i += 256) {
        int dd = i >> 6, ll = i & 63;
        ddt[((size_t)(b * Dm + d0 + dd)) * Lsz + l0 + ll] = pt[dd][ll];
    }
    if (tid < 64) {        // per-32 chunk-sums of the ROUNDED delta (consistency w/ scan)
        float s0 = 0.f, s1 = 0.f;
        #pragma unroll 16
        for (int q = 0; q < 32; ++q) {
            s0 += __uint_as_float(__float_as_uint(pt[tid][q]) << 16);
            s1 += __uint_as_float(__float_as_uint(pt[tid][32 + q]) << 16);
        }
        size_t sb = (size_t)(b * Dm + d0 + tid) * NCHUNK + lt * 2;
        sumdl[sb] = s0; sumdl[sb + 1] = s1;
    }

    // ---- B/C transpose to chunk-tiled bf16 (dt==0 blocks only) ----
    if (dt == 0) {
        #pragma unroll
        for (int pass = 0; pass < 2; ++pass) {
            __syncthreads();
            for (int i = tid; i < 4096; i += 256) {
                int l = i >> 6, e = i & 63;
                pt[e][l] = xdbl[(size_t)(b * Lsz + l0 + l) * Ee + Rr + pass * 64 + e];
            }
            __syncthreads();
            const int n = tid >> 2, q = tid & 3;
            const int cc = lt * 2 + (q >> 1), tt0 = (q & 1) * 16;
            unsigned short* dst = (pass ? Ct : Bt) +
                (((size_t)b * NCHUNK + cc) * Nst + n) * CLEN + tt0;
            u16x8 o0, o1;
            #pragma unroll
            for (int k = 0; k < 8; ++k) {
                o0[k] = (unsigned short)bf16r(pt[n][(q & 1) * 16 + (q >> 1) * 32 + k]);
                o1[k] = (unsigned short)bf16r(pt[n][(q & 1) * 16 + (q >> 1) * 32 + 8 + k]);
            }
            *reinterpret_cast<u16x8*>(dst)     = o0;
            *reinterpret_cast<u16x8*>(dst + 8) = o1;
        }
    }
}

// ---------------- K3a: local 32-step chunk scans (h0=0) -> hf; 8 chans/wave,
//                  B in registers (tiled bf16), zero LDS / zero barriers ----------------
__global__ __launch_bounds__(256) void k3a(const float* __restrict__ ddt,
                                           const unsigned short* __restrict__ Bt,
                                           const float* __restrict__ Alog,
                                           float* __restrict__ hf) {
    const int tid = threadIdx.x;
    const int w = __builtin_amdgcn_readfirstlane(tid >> 6);
    const int lane = tid & 63;
    const int c   = blockIdx.x & 63;       // chunk
    const int grp = blockIdx.x >> 6;       // 0..31
    const int chan0 = grp * 32 + w * 8;
    const int b = chan0 >> 9;
    const int t0 = c * CLEN;
    const unsigned short* bp = Bt + (((size_t)b * NCHUNK + c) * Nst + lane) * CLEN;
    u16x8 breg[4];
    #pragma unroll
    for (int i = 0; i < 4; ++i) breg[i] = *reinterpret_cast<const u16x8*>(bp + i * 8);

    const int tl = lane & 31;
    float A2[8], h[8], dpack[8];
    #pragma unroll
    for (int ch = 0; ch < 8; ++ch) {
        const int cc = chan0 + ch;
        A2[ch] = -expf(Alog[(size_t)(cc & 511) * Nst + lane]) * L2E;
        dpack[ch] = ddt[(size_t)cc * Lsz + t0 + tl];
        h[ch] = 0.f;
    }
    #pragma unroll
    for (int j = 0; j < CLEN; ++j) {
        float Bv = bf2f(breg[j >> 3][j & 7]);
        #pragma unroll
        for (int ch = 0; ch < 8; ++ch) {
            uint32_t wb = __float_as_uint(rdlane(dpack[ch], j));   // sgpr
            float sd = __uint_as_float(wb << 16);
            float su = __uint_as_float(wb & 0xffff0000u);
            h[ch] = fmaf(fexp2(sd * A2[ch]), h[ch], su * Bv);
        }
    }
    #pragma unroll
    for (int ch = 0; ch < 8; ++ch)
        hf[((size_t)(chan0 + ch) * NCHUNK + c) * Nst + lane] = h[ch];
}

// ---------------- K3b: sequential fix-up over 64 chunks; hf <- h0 (in place) ----------------
__global__ __launch_bounds__(256) void k3b(const float* __restrict__ Alog,
                                           const float* __restrict__ sumdl,
                                           float* __restrict__ hf) {
    const int tid = threadIdx.x;
    const int w = tid >> 6, lane = tid & 63;
    const int chan = blockIdx.x * 4 + w;
    const int d = chan & 511;
    const float A2 = -expf(Alog[(size_t)d * Nst + lane]) * L2E;
    const float sv = sumdl[chan * NCHUNK + lane];   // 64 chunk-sums, lane = chunk
    const size_t base = (size_t)chan * NCHUNK * Nst + lane;
    float hv[8], nx[8];
    #pragma unroll
    for (int i = 0; i < 8; ++i) hv[i] = hf[base + i * Nst];
    float h0 = 0.f;
    for (int g = 0; g < 8; ++g) {
        if (g < 7) {
            #pragma unroll
            for (int i = 0; i < 8; ++i) nx[i] = hf[base + ((g + 1) * 8 + i) * Nst];
        }
        #pragma unroll
        for (int i = 0; i < 8; ++i) {
            const int c = g * 8 + i;
            float P = fexp2(A2 * rdlane(sv, c));
            hf[base + c * Nst] = h0;              // h0 entering chunk c
            h0 = fmaf(P, h0, hv[i]);
        }
        #pragma unroll
        for (int i = 0; i < 8; ++i) hv[i] = nx[i];
    }
}

// ---------------- K3c: 32-step chunk scans from h0; fused epilogue out = y + x*D;
//   B/C in registers (tiled bf16); barrier-free main loop;
//   reduce pipelined 1 step behind (round-12/13 proven) ----------------
__global__ __launch_bounds__(256, 6) void k3c(const float* __restrict__ ddt,
                                              const unsigned short* __restrict__ Bt,
                                              const unsigned short* __restrict__ Ct,
                                              const float* __restrict__ Alog,
                                              const float* __restrict__ h0s,
                                              const float* __restrict__ x,
                                              const float* __restrict__ Dv,
                                              float* __restrict__ out) {
    __shared__ float part[4][8][68];       // per-wave, padded for b128 (8.7 KB)
    __shared__ float ystage[4][8][34];     // per-wave y staging (4.4 KB)
    const int tid = threadIdx.x;
    const int w = __builtin_amdgcn_readfirstlane(tid >> 6);
    const int lane = tid & 63;
    const int c   = blockIdx.x & 63;
    const int grp = blockIdx.x >> 6;
    const int chan0 = grp * 32 + w * 8;
    const int b = chan0 >> 9;
    const int t0 = c * CLEN;

    const unsigned short* bp = Bt + (((size_t)b * NCHUNK + c) * Nst + lane) * CLEN;
    const unsigned short* cp = Ct + (((size_t)b * NCHUNK + c) * Nst + lane) * CLEN;
    u16x8 breg[4], creg[4];
    #pragma unroll
    for (int i = 0; i < 4; ++i) {
        breg[i] = *reinterpret_cast<const u16x8*>(bp + i * 8);
        creg[i] = *reinterpret_cast<const u16x8*>(cp + i * 8);
    }

    const int tl = lane & 31;
    float A2[8], h[8], dpack[8];
    #pragma unroll
    for (int ch = 0; ch < 8; ++ch) {
        const int cc = chan0 + ch;
        A2[ch] = -expf(Alog[(size_t)(cc & 511) * Nst + lane]) * L2E;
        dpack[ch] = ddt[(size_t)cc * Lsz + t0 + tl];
        h[ch] = h0s[((size_t)cc * NCHUNK + c) * Nst + lane];
    }
    const int r8 = lane & 7, sg = lane >> 3;

    #pragma unroll
    for (int t = 0; t < CLEN; ++t) {
        // (1) issue reads of step t-1's partials (in-order DS within wave)
        float4 pa, pb;
        if (t > 0) {
            pa = *reinterpret_cast<const float4*>(&part[w][r8][sg * 8]);
            pb = *reinterpret_cast<const float4*>(&part[w][r8][sg * 8 + 4]);
        }
        // (2) scan step t (exp work hides the LDS read latency)
        float Bv = bf2f(breg[t >> 3][t & 7]);
        float Cv = bf2f(creg[t >> 3][t & 7]);
        #pragma unroll
        for (int ch = 0; ch < 8; ++ch) {
            uint32_t wb = __float_as_uint(rdlane(dpack[ch], t));
            float sd = __uint_as_float(wb << 16);
            float su = __uint_as_float(wb & 0xffff0000u);
            h[ch] = fmaf(fexp2(sd * A2[ch]), h[ch], su * Bv);
            part[w][ch][lane] = h[ch] * Cv;
        }
        // (3) finish step t-1's y-reduce
        if (t > 0) {
            float v = ((pa.x + pa.y) + (pa.z + pa.w)) + ((pb.x + pb.y) + (pb.z + pb.w));
            v += __shfl_xor(v, 8);
            v += __shfl_xor(v, 16);
            v += __shfl_xor(v, 32);
            if (lane < 8) ystage[w][lane][t - 1] = v;
        }
    }
    {   // final reduce (t = 31)
        float4 pa = *reinterpret_cast<const float4*>(&part[w][r8][sg * 8]);
        float4 pb = *reinterpret_cast<const float4*>(&part[w][r8][sg * 8 + 4]);
        float v = ((pa.x + pa.y) + (pa.z + pa.w)) + ((pb.x + pb.y) + (pb.z + pb.w));
        v += __shfl_xor(v, 8); v += __shfl_xor(v, 16); v += __shfl_xor(v, 32);
        if (lane < 8) ystage[w][lane][31] = v;
    }
    // fused epilogue: out[b, t0+t, d0+dd] = y + x*D  (coalesced 128B rows)
    __syncthreads();
    const int d0 = (grp * 32) & 511;
    for (int i = tid; i < 1024; i += 256) {
        int t = i >> 5, dd = i & 31;
        size_t gi = ((size_t)(b * Lsz + t0 + t)) * Dm + d0 + dd;
        out[gi] = ystage[dd >> 3][dd & 7][t] + x[gi] * Dv[d0 + dd];
    }
}

extern "C" void kernel_launch(void* const* d_in, const int* in_sizes, int n_in,
                              void* d_out, int out_size, void* d_ws, size_t ws_size,
                              hipStream_t stream) {
    const float* x    = (const float*)d_in[0];
    const float* Wxp  = (const float*)d_in[1];
    const float* Wdt  = (const float*)d_in[2];
    const float* bdt  = (const float*)d_in[3];
    const float* Alog = (const float*)d_in[4];
    const float* Dv   = (const float*)d_in[5];
    float* out = (float*)d_out;

    float* ws = (float*)d_ws;
    float*          xdbl    = ws;                                  // 655,360 f
    // hf (4,194,304 f) aliases the dead-after-k1 xbf/wbf region
    float*          hf      = ws + 655360;
    unsigned short* xbf     = (unsigned short*)(ws + 655360);      // 2,097,152 u16
    unsigned short* wbf     = (unsigned short*)(ws + 1703936);     // 81,920 u16
    float*          ddt     = ws + 4849664;                        // 2,097,152 f (packed u32)
    float*          sumdl   = ws + 6946816;                        // 65,536 f
    unsigned short* Bt      = (unsigned short*)(ws + 7012352);     // 262,144 u16
    unsigned short* Ct      = (unsigned short*)(ws + 7143424);     // 262,144 u16

    hipLaunchKernelGGL(kcast2,  dim3(1064), dim3(256), 0, stream, x, xbf, 262144, Wxp, wbf, 10240);
    hipLaunchKernelGGL(k1_mfma, dim3(640),  dim3(256), 0, stream, xbf, wbf, xdbl);
    hipLaunchKernelGGL(k2_delta,dim3(512),  dim3(256), 0, stream, xdbl, x, Wdt, bdt, ddt, sumdl, Bt, Ct);
    hipLaunchKernelGGL(k3a,     dim3(2048), dim3(256), 0, stream, ddt, Bt, Alog, hf);
    hipLaunchKernelGGL(k3b,     dim3(256),  dim3(256), 0, stream, Alog, sumdl, hf);
    hipLaunchKernelGGL(k3c,     dim3(2048), dim3(256), 0, stream, ddt, Bt, Ct, Alog, hf, x, Dv, out);
}